// Round 1
// baseline (894.856 us; speedup 1.0000x reference)
//
#include <hip/hip_runtime.h>
#include <math.h>

#define B_ 2
#define N_ 1000
#define F_ 8
#define T_ 12
#define H_ 64
#define G_ 24      // B*T
#define NF_ 8000   // N*F
#define ER_ 2000
#define EC_ 24000

__device__ __forceinline__ float sigf(float x){ return 1.0f/(1.0f+__expf(-x)); }

// ---------------------------------------------------------------- ws = mean over F
__global__ __launch_bounds__(64) void k_ws(const float* __restrict__ x, float* __restrict__ ws){
    int idx = blockIdx.x;            // g*N + n
    int h = threadIdx.x;
    int g = idx / N_, n = idx % N_;
    int b = g / T_, t = g % T_;
    const float* base = x + ((size_t)(b*N_+n)*F_*T_ + t)*H_ + h;
    float s = 0.f;
    #pragma unroll
    for (int f=0; f<F_; ++f) s += base[(size_t)f*T_*H_];
    ws[(size_t)idx*H_ + h] = s * (1.0f/F_);
}

// ---------------------------------------------------------------- y = xin @ W(64x64) + b
// FN=true: rows gathered from x as fn[g, j=n*F+f, :]
template<int R, bool FN>
__global__ __launch_bounds__(64) void k_mm64(const float* __restrict__ xin,
                                             const float* __restrict__ x,
                                             const float* __restrict__ W,
                                             const float* __restrict__ bias,
                                             float* __restrict__ y){
    __shared__ float row[R][64];
    int h = threadIdx.x;
    int r0 = blockIdx.x * R;
    for (int r=0;r<R;++r){
        int rr = r0 + r;
        if (FN){
            int g = rr / NF_, j = rr % NF_;
            int b = g / T_, t = g % T_, n = j / F_, f = j % F_;
            row[r][h] = x[((size_t)((b*N_+n)*F_+f)*T_ + t)*H_ + h];
        } else {
            row[r][h] = xin[(size_t)rr*64 + h];
        }
    }
    __syncthreads();
    float acc[R];
    float bv = bias[h];
    #pragma unroll
    for (int r=0;r<R;++r) acc[r]=bv;
    for (int k=0;k<64;++k){
        float w = W[k*64+h];
        #pragma unroll
        for (int r=0;r<R;++r) acc[r] += row[r][k]*w;
    }
    for (int r=0;r<R;++r) y[(size_t)(r0+r)*64 + h] = acc[r];
}

// ---------------------------------------------------------------- scatter-add messages
// 256 threads = 4 edges; idx = g*E + e
__global__ __launch_bounds__(256) void k_scatter(const float* __restrict__ y,
                                                 const int* __restrict__ src,
                                                 const int* __restrict__ dst,
                                                 const float* __restrict__ ew,
                                                 const float* __restrict__ lw,
                                                 const float* __restrict__ gate,
                                                 float* __restrict__ aggr,
                                                 int E, int nseg){
    int h = threadIdx.x & 63;
    int idx = blockIdx.x*4 + (threadIdx.x >> 6);
    int g = idx / E, e = idx % E;
    float gs = sigf(gate[0]);
    float mw = gs*ew[e] + (1.f-gs)*sigf(lw[e]);
    int s = src[e], d = dst[e];
    float v = mw * y[((size_t)g*nseg + s)*64 + h];
    atomicAdd(&aggr[((size_t)g*nseg + d)*64 + h], v);
}

// ---------------------------------------------------------------- u = relu(concat[aggr,x] @ Wu(128x64) + b)
template<int R, bool FN>
__global__ __launch_bounds__(64) void k_update(const float* __restrict__ aggr,
                                               const float* __restrict__ xin,
                                               const float* __restrict__ x,
                                               const float* __restrict__ Wu,
                                               const float* __restrict__ bu,
                                               float* __restrict__ u){
    __shared__ float ra[R][64], rx[R][64];
    int h = threadIdx.x;
    int r0 = blockIdx.x * R;
    for (int r=0;r<R;++r){
        int rr = r0 + r;
        ra[r][h] = aggr[(size_t)rr*64 + h];
        if (FN){
            int g = rr / NF_, j = rr % NF_;
            int b = g / T_, t = g % T_, n = j / F_, f = j % F_;
            rx[r][h] = x[((size_t)((b*N_+n)*F_+f)*T_ + t)*H_ + h];
        } else {
            rx[r][h] = xin[(size_t)rr*64 + h];
        }
    }
    __syncthreads();
    float acc[R];
    float bv = bu[h];
    #pragma unroll
    for (int r=0;r<R;++r) acc[r]=bv;
    for (int k=0;k<64;++k){
        float w = Wu[k*64+h];
        #pragma unroll
        for (int r=0;r<R;++r) acc[r] += ra[r][k]*w;
    }
    for (int k=0;k<64;++k){
        float w = Wu[(64+k)*64+h];
        #pragma unroll
        for (int r=0;r<R;++r) acc[r] += rx[r][k]*w;
    }
    for (int r=0;r<R;++r) u[(size_t)(r0+r)*64 + h] = fmaxf(acc[r], 0.f);
}

// ---------------------------------------------------------------- fusion MLP
template<int R>
__global__ __launch_bounds__(64) void k_fusion(const float* __restrict__ fnu,
                                               const float* __restrict__ wsu,
                                               const float* __restrict__ W1,
                                               const float* __restrict__ b1,
                                               const float* __restrict__ W2,
                                               const float* __restrict__ b2,
                                               float* __restrict__ fused){
    __shared__ float rf[R][64], rw[R][64], hid[R][64];
    int h = threadIdx.x;
    int r0 = blockIdx.x * R;
    for (int r=0;r<R;++r){
        int rr = r0 + r;           // g*NF + j
        int g = rr / NF_, j = rr % NF_;
        int n = j / F_;
        rf[r][h] = fnu[(size_t)rr*64 + h];
        rw[r][h] = wsu[((size_t)g*N_ + n)*64 + h];
    }
    __syncthreads();
    float acc[R];
    float bv = b1[h];
    #pragma unroll
    for (int r=0;r<R;++r) acc[r]=bv;
    for (int k=0;k<64;++k){
        float w = W1[k*64+h];
        #pragma unroll
        for (int r=0;r<R;++r) acc[r] += rf[r][k]*w;
    }
    for (int k=0;k<64;++k){
        float w = W1[(64+k)*64+h];
        #pragma unroll
        for (int r=0;r<R;++r) acc[r] += rw[r][k]*w;
    }
    for (int r=0;r<R;++r) hid[r][h] = fmaxf(acc[r], 0.f);
    __syncthreads();
    float acc2[R];
    float bv2 = b2[h];
    #pragma unroll
    for (int r=0;r<R;++r) acc2[r]=bv2;
    for (int k=0;k<64;++k){
        float w = W2[k*64+h];
        #pragma unroll
        for (int r=0;r<R;++r) acc2[r] += hid[r][k]*w;
    }
    for (int r=0;r<R;++r) fused[(size_t)(r0+r)*64 + h] = acc2[r];
}

// ---------------------------------------------------------------- per-row temporal transformer
__global__ __launch_bounds__(64) void k_transformer(
    const float* __restrict__ fused,
    const float* __restrict__ ln1g, const float* __restrict__ ln1b,
    const float* __restrict__ ln2g, const float* __restrict__ ln2b,
    const float* __restrict__ Wqkv, const float* __restrict__ bqkv,
    const float* __restrict__ Wo,   const float* __restrict__ bo,
    const float* __restrict__ W1,   const float* __restrict__ b1,
    const float* __restrict__ W2,   const float* __restrict__ b2,
    float* __restrict__ out)
{
    __shared__ float s[T_][64];
    __shared__ float h1[T_][64];      // LN out; later re-used for attention output o
    __shared__ float buf[T_*256];     // qkv (t*192+c) then FFN hidden (t*256+c)
    int h = threadIdx.x;
    int r = blockIdx.x;               // (b*N+n)*F + f
    int b = r / (N_*F_);
    int rem = r % (N_*F_);
    int n = rem / F_, f = rem % F_;
    for (int t=0;t<T_;++t){
        int g = b*T_ + t;
        s[t][h] = fused[((size_t)g*NF_ + n*F_ + f)*64 + h];
    }
    __syncthreads();
    // LN1 -> h1
    {
        float gg = ln1g[h], bb = ln1b[h];
        for (int t=0;t<T_;++t){
            float v = s[t][h];
            float sum = v;
            for (int off=32; off>0; off>>=1) sum += __shfl_xor(sum, off, 64);
            float mean = sum * (1.0f/64.0f);
            float d = v - mean;
            float vs = d*d;
            for (int off=32; off>0; off>>=1) vs += __shfl_xor(vs, off, 64);
            h1[t][h] = d * rsqrtf(vs*(1.0f/64.0f) + 1e-5f) * gg + bb;
        }
    }
    __syncthreads();
    // QKV
    for (int c=0;c<3;++c){
        float acc[T_];
        float bv = bqkv[c*64+h];
        #pragma unroll
        for (int t=0;t<T_;++t) acc[t]=bv;
        for (int k=0;k<64;++k){
            float w = Wqkv[k*192 + c*64 + h];
            #pragma unroll
            for (int t=0;t<T_;++t) acc[t] += h1[t][k]*w;
        }
        for (int t=0;t<T_;++t) buf[t*192 + c*64 + h] = acc[t];
    }
    __syncthreads();
    // attention (48 lanes: head = h/12, qt = h%12), write o into h1
    if (h < 48){
        int head = h / 12, qt = h % 12;
        float sc[T_];
        float mx = -1e30f;
        for (int kt=0;kt<T_;++kt){
            float a = 0.f;
            #pragma unroll
            for (int d=0; d<16; ++d)
                a += buf[qt*192 + head*16 + d] * buf[kt*192 + 64 + head*16 + d];
            a *= 0.25f;
            sc[kt] = a;
            mx = fmaxf(mx, a);
        }
        float den = 0.f;
        for (int kt=0;kt<T_;++kt){ sc[kt] = __expf(sc[kt]-mx); den += sc[kt]; }
        float inv = 1.0f/den;
        for (int d=0; d<16; ++d){
            float acc = 0.f;
            for (int kt=0;kt<T_;++kt) acc += sc[kt]*buf[kt*192 + 128 + head*16 + d];
            h1[qt][head*16 + d] = acc*inv;
        }
    }
    __syncthreads();
    // proj + residual
    {
        float acc[T_];
        float bv = bo[h];
        #pragma unroll
        for (int t=0;t<T_;++t) acc[t]=bv;
        for (int k=0;k<64;++k){
            float w = Wo[k*64+h];
            #pragma unroll
            for (int t=0;t<T_;++t) acc[t] += h1[t][k]*w;
        }
        for (int t=0;t<T_;++t) s[t][h] += acc[t];
    }
    __syncthreads();
    // LN2 -> h1
    {
        float gg = ln2g[h], bb = ln2b[h];
        for (int t=0;t<T_;++t){
            float v = s[t][h];
            float sum = v;
            for (int off=32; off>0; off>>=1) sum += __shfl_xor(sum, off, 64);
            float mean = sum * (1.0f/64.0f);
            float d = v - mean;
            float vs = d*d;
            for (int off=32; off>0; off>>=1) vs += __shfl_xor(vs, off, 64);
            h1[t][h] = d * rsqrtf(vs*(1.0f/64.0f) + 1e-5f) * gg + bb;
        }
    }
    __syncthreads();
    // FFN1 + exact gelu -> buf[t*256+c]
    for (int c=0;c<4;++c){
        float acc[T_];
        float bv = b1[c*64+h];
        #pragma unroll
        for (int t=0;t<T_;++t) acc[t]=bv;
        for (int k=0;k<64;++k){
            float w = W1[k*256 + c*64 + h];
            #pragma unroll
            for (int t=0;t<T_;++t) acc[t] += h1[t][k]*w;
        }
        for (int t=0;t<T_;++t){
            float a = acc[t];
            buf[t*256 + c*64 + h] = 0.5f*a*(1.0f + erff(a*0.70710678118654752f));
        }
    }
    __syncthreads();
    // FFN2 + residual + mean over T
    {
        float acc[T_];
        float bv = b2[h];
        #pragma unroll
        for (int t=0;t<T_;++t) acc[t]=bv;
        for (int k=0;k<256;++k){
            float w = W2[k*64+h];
            #pragma unroll
            for (int t=0;t<T_;++t) acc[t] += buf[t*256+k]*w;
        }
        float m = 0.f;
        #pragma unroll
        for (int t=0;t<T_;++t) m += s[t][h] + acc[t];
        out[(size_t)r*64 + h] = m * (1.0f/T_);
    }
}

// ----------------------------------------------------------------
extern "C" void kernel_launch(void* const* d_in, const int* in_sizes, int n_in,
                              void* d_out, int out_size, void* d_ws, size_t ws_size,
                              hipStream_t stream) {
    const float* x      = (const float*)d_in[0];
    const int*   r_ei   = (const int*)  d_in[1];
    const float* r_ea   = (const float*)d_in[2];
    const int*   c_ei   = (const int*)  d_in[3];
    const float* c_ew   = (const float*)d_in[4];
    const float* rvWlin = (const float*)d_in[5];
    const float* rvblin = (const float*)d_in[6];
    const float* rvWupd = (const float*)d_in[7];
    const float* rvbupd = (const float*)d_in[8];
    const float* rvgate = (const float*)d_in[9];
    const float* rvlw   = (const float*)d_in[10];
    const float* csWlin = (const float*)d_in[11];
    const float* csblin = (const float*)d_in[12];
    const float* csWupd = (const float*)d_in[13];
    const float* csbupd = (const float*)d_in[14];
    const float* csgate = (const float*)d_in[15];
    const float* cslw   = (const float*)d_in[16];
    const float* fuW1   = (const float*)d_in[17];
    const float* fub1   = (const float*)d_in[18];
    const float* fuW2   = (const float*)d_in[19];
    const float* fub2   = (const float*)d_in[20];
    const float* ln1g   = (const float*)d_in[21];
    const float* ln1b   = (const float*)d_in[22];
    const float* ln2g   = (const float*)d_in[23];
    const float* ln2b   = (const float*)d_in[24];
    const float* Wqkv   = (const float*)d_in[25];
    const float* bqkv   = (const float*)d_in[26];
    const float* Wo     = (const float*)d_in[27];
    const float* bo     = (const float*)d_in[28];
    const float* ffW1   = (const float*)d_in[29];
    const float* ffb1   = (const float*)d_in[30];
    const float* ffW2   = (const float*)d_in[31];
    const float* ffb2   = (const float*)d_in[32];

    float* wsp  = (float*)d_ws;
    float* FNY  = wsp;                               // 12,288,000  (later reused as FNU)
    float* FNA  = wsp + 12288000;                    // 12,288,000  (later reused as FUSED)
    float* WS   = wsp + 24576000;                    //  1,536,000
    float* WSY  = wsp + 26112000;                    //  1,536,000
    float* WSA  = wsp + 27648000;                    //  1,536,000
    float* WSU  = wsp + 29184000;                    //  1,536,000
    float* outp = (float*)d_out;

    hipMemsetAsync(FNA, 0, (size_t)12288000*sizeof(float), stream);
    hipMemsetAsync(WSA, 0, (size_t)1536000*sizeof(float), stream);

    // watershed repr
    k_ws<<<G_*N_, 64, 0, stream>>>(x, WS);
    // node linear transforms
    k_mm64<8,false><<<(G_*N_)/8, 64, 0, stream>>>(WS, nullptr, rvWlin, rvblin, WSY);
    k_mm64<8,true ><<<(G_*NF_)/8, 64, 0, stream>>>(nullptr, x, csWlin, csblin, FNY);
    // gated scatter-add
    k_scatter<<<(G_*ER_)/4, 256, 0, stream>>>(WSY, r_ei, r_ei+ER_, r_ea, rvlw, rvgate, WSA, ER_, N_);
    k_scatter<<<(G_*EC_)/4, 256, 0, stream>>>(FNY, c_ei, c_ei+EC_, c_ew, cslw, csgate, FNA, EC_, NF_);
    // update MLPs
    k_update<8,false><<<(G_*N_)/8, 64, 0, stream>>>(WSA, WS, nullptr, rvWupd, rvbupd, WSU);
    k_update<8,true ><<<(G_*NF_)/8, 64, 0, stream>>>(FNA, nullptr, x, csWupd, csbupd, FNY); // FNU = FNY
    // fusion (writes into FNA region = FUSED)
    k_fusion<8><<<(G_*NF_)/8, 64, 0, stream>>>(FNY, WSU, fuW1, fub1, fuW2, fub2, FNA);
    // temporal transformer + time-mean -> out
    k_transformer<<<B_*N_*F_, 64, 0, stream>>>(FNA, ln1g, ln1b, ln2g, ln2b,
                                               Wqkv, bqkv, Wo, bo, ffW1, ffb1, ffW2, ffb2,
                                               outp);
}